// Round 10
// baseline (3480.553 us; speedup 1.0000x reference)
//
#include <hip/hip_runtime.h>
#include <math.h>

#define NPTS 3072
#define BLK  256
#define NW   4
#define NSL  8          // slots per lane: 8*64 = 512 >= max class size (~307+-17, +12 sigma)
#define NKB  48         // fallback batches: 48*64 = 3072
#define NCLS 10

#pragma clang fp contract(off)

__device__ __forceinline__ unsigned umin32(unsigned a, unsigned b) { return a < b ? a : b; }

// 4-step DPP row_shr chain: lanes 15/31/47/63 end with the min of their 16-lane row.
__device__ __forceinline__ unsigned rowmin4_u32(unsigned x) {
    unsigned t;
    t = (unsigned)__builtin_amdgcn_update_dpp(-1, (int)x, 0x111, 0xF, 0xF, false); x = x < t ? x : t; // row_shr:1
    t = (unsigned)__builtin_amdgcn_update_dpp(-1, (int)x, 0x112, 0xF, 0xF, false); x = x < t ? x : t; // row_shr:2
    t = (unsigned)__builtin_amdgcn_update_dpp(-1, (int)x, 0x114, 0xF, 0xF, false); x = x < t ? x : t; // row_shr:4
    t = (unsigned)__builtin_amdgcn_update_dpp(-1, (int)x, 0x118, 0xF, 0xF, false); x = x < t ? x : t; // row_shr:8
    return x;
}

// wave-wide u32 min: 4 DPP steps, then 4 parallel readlanes + scalar min tree (R6-proven).
__device__ __forceinline__ unsigned wavemin_u32(unsigned x) {
    unsigned r = rowmin4_u32(x);
    unsigned a = (unsigned)__builtin_amdgcn_readlane((int)r, 15);
    unsigned b = (unsigned)__builtin_amdgcn_readlane((int)r, 31);
    unsigned c = (unsigned)__builtin_amdgcn_readlane((int)r, 47);
    unsigned d = (unsigned)__builtin_amdgcn_readlane((int)r, 63);
    return umin32(umin32(a, b), umin32(c, d));
}

__device__ __forceinline__ float readlanef(float v, int l) {
    return __int_as_float(__builtin_amdgcn_readlane(__float_as_int(v), l));
}

// In-walk sweep over NS live slots (NS = ceil(cnt_c/64), dispatched per walk).
template<int NS>
__device__ __forceinline__ void sweep_step(const float (&sxr)[NSL], const float (&syr)[NSL],
                                           const float (&szr)[NSL], const unsigned (&mmr)[NSL],
                                           float pcx, float pcy, float pcz,
                                           unsigned &kbest, unsigned &mbest,
                                           float &bx, float &by, float &bz)
{
    float ss[NS];
    #pragma unroll
    for (int i = 0; i < NS; ++i) {
        float dx = pcx - sxr[i], dy = pcy - syr[i], dz = pcz - szr[i];
        ss[i] = (dx*dx + dy*dy) + dz*dz;   // ref order, contract off
    }
    float m;
    if constexpr (NS == 5)
        m = fminf(fminf(fminf(ss[0], ss[1]), fminf(ss[2], ss[3])), ss[4]);
    else if constexpr (NS == 6)
        m = fminf(fminf(fminf(ss[0], ss[1]), fminf(ss[2], ss[3])), fminf(ss[4], ss[5]));
    else
        m = fminf(fminf(fminf(ss[0], ss[1]), fminf(ss[2], ss[3])),
                  fminf(fminf(ss[4], ss[5]), fminf(ss[6], ss[7])));
    kbest = __float_as_uint(m);            // nonneg floats: bits order == value order
    unsigned mb = 0xFFFFFFFFu;
    #pragma unroll
    for (int i = 0; i < NS; ++i) {
        unsigned ci = (ss[i] == m) ? mmr[i] : 0xFFFFFFFFu;
        mb = umin32(mb, ci);
    }
    mbest = mb;
    bx = sxr[0]; by = syr[0]; bz = szr[0];
    #pragma unroll
    for (int i = 1; i < NS; ++i) {         // metas unique (sentinel != any winner)
        bool w = (mmr[i] == mb);
        bx = w ? sxr[i] : bx; by = w ? syr[i] : by; bz = w ? szr[i] : bz;
    }
}

// poison by pos (low 12 bits of meta; unique per slot; sentinel 0xFFF never matches)
template<int NS>
__device__ __forceinline__ void poison_pos(float (&sxr)[NSL], const unsigned (&mmr)[NSL],
                                           unsigned wpos)
{
    #pragma unroll
    for (int i = 0; i < NS; ++i)
        if ((mmr[i] & 0xFFFu) == wpos) sxr[i] = 3e19f;  // poisoned slot: ss -> +inf
}

// visited-bit helpers over 8 uniform u64 words (class-local idx 0..511); explicit
// selects (no dynamically-indexed array -> stays in registers, rule-#20-safe)
__device__ __forceinline__ bool nn_unv(int e, int base_c,
        unsigned long long vb0, unsigned long long vb1, unsigned long long vb2,
        unsigned long long vb3, unsigned long long vb4, unsigned long long vb5,
        unsigned long long vb6, unsigned long long vb7)
{
    int ix = e - base_c;
    int w = ix >> 6;
    unsigned long long vw = w==0?vb0 : w==1?vb1 : w==2?vb2 : w==3?vb3
                          : w==4?vb4 : w==5?vb5 : w==6?vb6 : vb7;
    return (e != 0xFFF) && !((vw >> (ix & 63)) & 1ull);
}
__device__ __forceinline__ void nn_setv(int ix,
        unsigned long long &vb0, unsigned long long &vb1, unsigned long long &vb2,
        unsigned long long &vb3, unsigned long long &vb4, unsigned long long &vb5,
        unsigned long long &vb6, unsigned long long &vb7)
{
    unsigned long long bit = 1ull << (ix & 63);
    int w = ix >> 6;
    vb0 = (w==0) ? (vb0|bit) : vb0;
    vb1 = (w==1) ? (vb1|bit) : vb1;
    vb2 = (w==2) ? (vb2|bit) : vb2;
    vb3 = (w==3) ? (vb3|bit) : vb3;
    vb4 = (w==4) ? (vb4|bit) : vb4;
    vb5 = (w==5) ? (vb5|bit) : vb5;
    vb6 = (w==6) ? (vb6|bit) : vb6;
    vb7 = (w==7) ? (vb7|bit) : vb7;
}

// R10 phase-A inner iteration: NN4-list fast path + R6 sweep fallback.
// HIT exactness: knn4[pos] = global top-4 same-class neighbors sorted by
// (key,meta) with bit-identical keys to the sweep; first unvisited entry ==
// exact argmin over unvisited (all smaller candidates are in-list & visited;
// off-list candidates > list[3]). MISS: R6 sweep (exact), poison kept current
// every step. Visited bits vb0..7 uniform; updated every step.
#define WALK_INNER(NS)                                                          \
    for (int k = 0; k < iters; ++k) {                                           \
        int nxt = -1;                                                           \
        if (iters - k > 4) {              /* skip list at walk tail (perf only) */ \
            unsigned long long lst = knn4[pos];       /* uniform ds_read_b64 */ \
            unsigned llo = (unsigned)__builtin_amdgcn_readfirstlane((int)(unsigned)lst);         \
            unsigned lhi = (unsigned)__builtin_amdgcn_readfirstlane((int)(unsigned)(lst >> 32)); \
            int e0 = (int)(llo & 0xFFFFu), e1 = (int)(llo >> 16);               \
            int e2 = (int)(lhi & 0xFFFFu), e3 = (int)(lhi >> 16);               \
            bool u0 = nn_unv(e0, base_c, vb0,vb1,vb2,vb3,vb4,vb5,vb6,vb7);      \
            bool u1 = nn_unv(e1, base_c, vb0,vb1,vb2,vb3,vb4,vb5,vb6,vb7);      \
            bool u2 = nn_unv(e2, base_c, vb0,vb1,vb2,vb3,vb4,vb5,vb6,vb7);      \
            bool u3 = nn_unv(e3, base_c, vb0,vb1,vb2,vb3,vb4,vb5,vb6,vb7);      \
            nxt = u0 ? e0 : u1 ? e1 : u2 ? e2 : u3 ? e3 : -1;                   \
        }                                                                       \
        if (nxt >= 0) {                                   /* HIT */             \
            pos = nxt;                                                          \
            float4 wp = gpts[pos];        /* uniform; consumed only on miss */  \
            pcx = wp.x; pcy = wp.y; pcz = wp.z;                                 \
        } else {                                          /* MISS: exact sweep */ \
            unsigned kbest, mbest; float bx, by, bz;                            \
            sweep_step<NS>(sxr, syr, szr, mmr, pcx, pcy, pcz, kbest, mbest, bx, by, bz); \
            unsigned wk = wavemin_u32(kbest);                                   \
            bool cand = (kbest == wk);                                          \
            unsigned long long msk = __ballot(cand);                            \
            if (msk & (msk - 1)) {                   /* exact-bit key tie: rare */ \
                unsigned wm2 = wavemin_u32(cand ? mbest : 0xFFFFFFFFu);         \
                msk = __ballot(cand && (mbest == wm2));                         \
            }                                                                   \
            int wl = __ffsll((unsigned long long)msk) - 1;                      \
            unsigned wm = (unsigned)__builtin_amdgcn_readlane((int)mbest, wl);  \
            pos = (int)(wm & 0xFFFu);                                           \
            pcx = readlanef(bx, wl); pcy = readlanef(by, wl); pcz = readlanef(bz, wl); \
        }                                                                       \
        poison_pos<NS>(sxr, mmr, (unsigned)pos);                                \
        nn_setv(pos - base_c, vb0,vb1,vb2,vb3,vb4,vb5,vb6,vb7);                 \
        *((lane == 0) ? &recM16[u] : &sdump[lane]) = (unsigned short)pos;       \
        ++u;                                                                    \
    }

__global__ __launch_bounds__(BLK)
void frustum_cluster(const float* __restrict__ pts,
                     const int* __restrict__ lblg,
                     const float* __restrict__ anch,
                     int* __restrict__ out,
                     int* __restrict__ ws)
{
    const int tid  = threadIdx.x;
    const int lane = tid & 63;
    const int wid  = tid >> 6;

    // ---------------- global workspace ----------------
    int*    dlg    = ws + 16;                          // 3072 ints: per-point label
    float4* gstats = (float4*)(ws + 8192);             // per-cluster stats

    // ---------------- LDS (~87 KB; gfx950 has 160 KB/CU) ----------------
    __shared__ float4 gpts[NPTS];                      // class-grouped points; epilogue: ordered clusters
    __shared__ unsigned long long knn4[NPTS];          // per-point top-4 same-class NN (4x u16 pos)
    __shared__ unsigned short recM16[NPTS];            // visit order -> pos
    __shared__ unsigned short startv[NPTS];            // cluster starts; (b)/(c): ids; (d)-(f): remap16
    __shared__ unsigned short sdump[64];               // dummy target for predicated writes
    __shared__ unsigned short walkS16[65];             // walk w's first visit index; NPTS = absent
    __shared__ unsigned short walkCls16[16];           // walk w's class
    __shared__ float amdxy[NCLS], amdz[NCLS];
    __shared__ unsigned vthr[NCLS], wthr[NCLS];        // sqrt-free compare thresholds
    __shared__ int cntL[NCLS], curL[NCLS], baseL[NCLS];
    __shared__ int cntC[NCLS], curC[NCLS], baseC[NCLS];
    __shared__ int cntW[16], baseW[16];                // clusters per walk / prefix
    __shared__ int p0s, nclusS;

    if (tid < NCLS) {
        float l = anch[tid*3+0], w = anch[tid*3+1], h = anch[tid*3+2];
        amdxy[tid] = fmaxf(l, w);
        amdz[tid]  = h;
        float r2 = sqrtf((l*l + w*w) + h*h) * 0.5f;    // norm(anchor)/2, ref op order
        unsigned lo = 0u, hi = 0x7F7FFFFFu;
        while (hi - lo > 1u) {
            unsigned mid = lo + ((hi - lo) >> 1);
            if (sqrtf(__uint_as_float(mid)) <= r2) lo = mid; else hi = mid;
        }
        vthr[tid] = lo;
        lo = 0u; hi = 0x7F7FFFFFu;
        while (hi - lo > 1u) {
            unsigned mid = lo + ((hi - lo) >> 1);
            if (sqrtf(__uint_as_float(mid)) < r2) lo = mid; else hi = mid;
        }
        wthr[tid] = lo;
        cntL[tid] = 0; curL[tid] = 0; cntC[tid] = 0; curC[tid] = 0;
    }
    if (tid < 65) walkS16[tid] = (unsigned short)NPTS;
    if (tid < 16) { walkCls16[tid] = 0; cntW[tid] = 0; }
    __syncthreads();
    for (int j = tid; j < NPTS; j += BLK) atomicAdd(&cntL[lblg[j]], 1);
    __syncthreads();
    if (tid == 0) { int acc = 0; for (int c = 0; c < NCLS; ++c) { baseL[c] = acc; acc += cntL[c]; } }
    __syncthreads();
    // scatter into class-grouped layout; w = prebaked meta (id<<16 | cls<<12 | pos)
    for (int j = tid; j < NPTS; j += BLK) {
        int c = lblg[j];
        int pos = baseL[c] + atomicAdd(&curL[c], 1);
        float4 e;
        e.x = pts[3*j]; e.y = pts[3*j+1]; e.z = pts[3*j+2];
        e.w = __uint_as_float(((unsigned)j << 16) | ((unsigned)c << 12) | (unsigned)pos);
        gpts[pos] = e;
        if (j == 0) p0s = pos;
    }
    __syncthreads();   // scatter + p0s visible

    // ========== NN4 precompute: all 4 waves, branchless sorted-4 insertion ==========
    // Sorted ascending by (key, meta) lexicographic; key bits == the sweep's ss bits
    // (same gpts operands, same expression order, contract off). Self excluded via
    // key=+inf. Packed as 4x u16 pos fields (sentinel 0xFFF).
    for (int r = 0; r < NPTS / BLK; ++r) {
        int p = tid + (r << 8);
        float4 ep = gpts[p];
        unsigned mp = __float_as_uint(ep.w);
        int pcls = (int)((mp >> 12) & 15u);
        int b = baseL[pcls], cnt = cntL[pcls];
        unsigned k0=~0u,k1=~0u,k2=~0u,k3=~0u, m0=~0u,m1=~0u,m2=~0u,m3=~0u;
        for (int j = 0; j < cnt; ++j) {
            int q = b + j;
            float4 eq = gpts[q];
            float dx = ep.x - eq.x, dy = ep.y - eq.y, dz = ep.z - eq.z;
            float ssq = (dx*dx + dy*dy) + dz*dz;
            unsigned kk = (q == p) ? 0xFFFFFFFFu : __float_as_uint(ssq);
            unsigned mm = __float_as_uint(eq.w);
            bool l3 = (kk<k3)|((kk==k3)&(mm<m3)); k3=l3?kk:k3; m3=l3?mm:m3;
            bool s2 = (k3<k2)|((k3==k2)&(m3<m2));
            unsigned tk=k2, tm=m2; k2=s2?k3:k2; m2=s2?m3:m2; k3=s2?tk:k3; m3=s2?tm:m3;
            bool s1 = (k2<k1)|((k2==k1)&(m2<m1));
            tk=k1; tm=m1; k1=s1?k2:k1; m1=s1?m2:m1; k2=s1?tk:k2; m2=s1?tm:m2;
            bool s0 = (k1<k0)|((k1==k0)&(m1<m0));
            tk=k0; tm=m0; k0=s0?k1:k0; m0=s0?m1:m0; k1=s0?tk:k1; m1=s0?tm:m1;
        }
        knn4[p] =  (unsigned long long)(m0 & 0xFFFu)
                | ((unsigned long long)(m1 & 0xFFFu) << 16)
                | ((unsigned long long)(m2 & 0xFFFu) << 32)
                | ((unsigned long long)(m3 & 0xFFFu) << 48);
    }
    __syncthreads();   // knn4 ready

    // ================= PHASE A: single-wave walk (wave 0), NN4-accelerated =================
    if (wid == 0) {
        int baseLn = 0, cntLn = 0;
        if (lane < NCLS) { baseLn = baseL[lane]; cntLn = cntL[lane]; }
        const int p0 = p0s;
        int pos = p0;
        int cls = lblg[0];
        unsigned walked = 1u << cls;
        float sxr[NSL], syr[NSL], szr[NSL];
        unsigned mmr[NSL];
        float pcx = pts[0], pcy = pts[1], pcz = pts[2];
        unsigned long long vb0=0,vb1=0,vb2=0,vb3=0,vb4=0,vb5=0,vb6=0,vb7=0;
        int u = 1;                                     // next visit index
        if (lane == 0) recM16[0] = (unsigned short)p0;

        for (int wix = 0; wix < NCLS; ++wix) {         // max 10 walks
            if (lane == 0) {                           // walk boundary record
                walkS16[wix]   = (unsigned short)(u - 1);
                walkCls16[wix] = (unsigned short)cls;
            }
            // ---- walk reload: class cls, excluding current pos ----
            int base_c = __builtin_amdgcn_readlane(baseLn, cls);
            int cnt_c  = __builtin_amdgcn_readlane(cntLn, cls);
            #pragma unroll
            for (int i = 0; i < NSL; ++i) {            // full 8: slots >= nsC stay poisoned
                int off = lane + (i << 6);
                int p = base_c + off;
                bool in = off < cnt_c;
                float4 e = gpts[in ? p : 0];
                bool v = in && (p != pos);             // fresh class: only current point visited
                sxr[i] = v ? e.x : 3e19f;
                syr[i] = v ? e.y : 0.f;
                szr[i] = v ? e.z : 0.f;
                mmr[i] = in ? __float_as_uint(e.w) : 0xFFFFFFFFu;  // sentinel meta for dead slots
            }
            vb0=0; vb1=0; vb2=0; vb3=0; vb4=0; vb5=0; vb6=0; vb7=0;
            nn_setv(pos - base_c, vb0,vb1,vb2,vb3,vb4,vb5,vb6,vb7);
            int nsC = (cnt_c + 63) >> 6;
            int iters = cnt_c - 1;

            if (nsC <= 5)      { WALK_INNER(5) }
            else if (nsC == 6) { WALK_INNER(6) }
            else               { WALK_INNER(8) }

            if (u >= NPTS) break;

            // ---- fallback (9x total): nearest point of any un-walked class ----
            {
                unsigned kbest = 0xFFFFFFFFu, mbest = 0xFFFFFFFFu;
                float bx = 0.f, by = 0.f, bz = 0.f;
                for (int k2 = 0; k2 < NKB; ++k2) {
                    int p = lane + (k2 << 6);
                    float4 e = gpts[p];
                    unsigned meta = __float_as_uint(e.w);
                    float dx = pcx - e.x, dy = pcy - e.y, dz = pcz - e.z;
                    float s = (dx*dx + dy*dy) + dz*dz;
                    unsigned key = __float_as_uint(s);
                    bool ok = !((walked >> ((meta >> 12) & 15u)) & 1u);
                    if (ok && (key < kbest || (key == kbest && meta < mbest))) {
                        kbest = key; mbest = meta; bx = e.x; by = e.y; bz = e.z;
                    }
                }
                unsigned wk = wavemin_u32(kbest);
                bool cand = (kbest == wk);
                unsigned long long msk = __ballot(cand);
                if (msk & (msk - 1)) {
                    unsigned wm2 = wavemin_u32(cand ? mbest : 0xFFFFFFFFu);
                    msk = __ballot(cand && (mbest == wm2));
                }
                int wl = __ffsll((unsigned long long)msk) - 1;
                unsigned wm = (unsigned)__builtin_amdgcn_readlane((int)mbest, wl);
                float pix = readlanef(bx, wl), piy = readlanef(by, wl), piz = readlanef(bz, wl);
                pos = (int)(wm & 0xFFFu);
                cls = (int)((wm >> 12) & 15u);
                walked |= 1u << cls;
                *((lane == 0) ? &recM16[u] : &sdump[lane]) = (unsigned short)pos;
                pcx = pix; pcy = piy; pcz = piz;
                ++u;
            }
        }
    }
    __syncthreads();   // join A

    // ================= PHASE B: lane-parallel walk replay (wave 0) =================
    if (wid == 0) {
        int w = lane;
        int sW = (int)walkS16[w];                      // NPTS if absent (w >= #walks)
        int eW = (int)walkS16[w + 1];
        bool exists = sW < NPTS;
        int cls = (int)walkCls16[exists ? w : 0];
        float axy = amdxy[cls], az = amdz[cls];
        unsigned Vc = vthr[cls];
        int pos0 = (int)recM16[exists ? sW : 0];
        float4 pe = gpts[pos0];
        float prevx = pe.x, prevy = pe.y, prevz = pe.z;
        float sx = prevx, sy = prevy, sz = prevz, scnt = 1.0f;
        int cnt = 1;
        if (exists) startv[sW] = (unsigned short)sW;   // walk's first visit starts a cluster
        int u = sW + 1;
        int posn = (int)recM16[(exists && u < eW) ? u : 0];   // prefetched meta
        for (;;) {
            unsigned long long alive = __ballot(u < eW);
            if (!alive) break;
            bool act = (u < eW);
            float4 ec = gpts[act ? posn : 0];
            int posn2 = (int)recM16[(u + 1 < eW) ? (u + 1) : 0];
            float pix = ec.x, piy = ec.y, piz = ec.z;
            float dx = prevx - pix, dy = prevy - piy, dz = prevz - piz;
            float seS = (dx*dx + dy*dy) + dz*dz;       // == A's winner key bits
            bool a1 = (fabsf(dx) > axy) | (fabsf(dy) > axy) | (fabsf(dz) > az);
            float icx = sx / scnt, icy = sy / scnt, icz = sz / scnt;
            float ex = icx - pix, ey = icy - piy, ez = icz - piz;
            float seC = (ex*ex + ey*ey) + ez*ez;
            bool nc = a1 | (__float_as_uint(seS) > Vc) | (__float_as_uint(seC) > Vc);
            if (act & nc) startv[sW + cnt] = (unsigned short)u;
            cnt += (act & nc) ? 1 : 0;
            scnt = nc ? 1.0f : (scnt + 1.0f);          // scnt >= 1 always (no div-by-0)
            sx = nc ? pix : (sx + pix);
            sy = nc ? piy : (sy + piy);
            sz = nc ? piz : (sz + piz);
            prevx = pix; prevy = piy; prevz = piz;
            posn = posn2;
            ++u;
        }
        if (exists) cntW[w] = cnt;
    }
    __syncthreads();   // join B

    if (tid == 0) {    // prefix over per-walk cluster counts
        int acc = 0;
        for (int c = 0; c < NCLS; ++c) { baseW[c] = acc; acc += cntW[c]; }
        nclusS = acc - 1;                              // lab semantics: starts - 1
    }
    __syncthreads();

    // compaction: left-shift staged starts (walks in order; baseW[w] <= s_w provably)
    if (wid == 0) {
        for (int w2 = 0; w2 < NCLS; ++w2) {
            int sW = (int)walkS16[w2];
            if (sW >= NPTS) break;                     // walks contiguous from 0
            int bW = baseW[w2], cW = cntW[w2];
            if (bW == sW) continue;
            for (int j = lane; j < cW; j += 64) {
                unsigned short v = startv[sW + j];
                startv[bW + j] = v;
            }
        }
    }
    __syncthreads();
    const int nclus = nclusS;

    // ---------------- epilogue (R6-proven) ----------------
    // (a) runs in visit order -> per-cluster stats + dl to global
    for (int c2 = tid; c2 <= nclus; c2 += BLK) {
        int s0 = startv[c2];
        int s1e = (c2 < nclus) ? (int)startv[c2+1] : NPTS;
        float ax = 0.f, ay = 0.f, az = 0.f;
        int clsF = 0;
        for (int s = s0; s < s1e; ++s) {
            float4 e = gpts[recM16[s]];
            unsigned pk = __float_as_uint(e.w);
            if (s == s0) clsF = (int)((pk >> 12) & 15u);
            ax = ax + e.x; ay = ay + e.y; az = az + e.z;
            dlg[pk >> 16] = c2;
        }
        if (c2 < nclus) {
            float fc = (float)(s1e - s0);
            float4 g;
            g.x = ax / fc; g.y = ay / fc; g.z = az / fc;
            g.w = __uint_as_float(((unsigned)(s1e - s0) << 4) | (unsigned)clsF);
            gstats[c2] = g;
        }
    }
    __syncthreads();

    // (a2) bucket counts per class over clusters
    for (int c2 = tid; c2 < nclus; c2 += BLK)
        atomicAdd(&cntC[__float_as_uint(gstats[c2].w) & 15u], 1);
    __syncthreads();
    if (tid == 0) { int acc = 0; for (int c = 0; c < NCLS; ++c) { baseC[c] = acc; acc += cntC[c]; } }
    __syncthreads();

    // (b) scatter clusters into class buckets (recM16 = count, startv = cluster id)
    for (int c2 = tid; c2 < nclus; c2 += BLK) {
        unsigned gw = __float_as_uint(gstats[c2].w);
        int cl = (int)(gw & 15u);
        int slot = baseC[cl] + atomicAdd(&curC[cl], 1);
        recM16[slot] = (unsigned short)(gw >> 4);
        startv[slot] = (unsigned short)c2;
    }
    __syncthreads();

    // (c) class-local stable rank (counts desc, id asc) -> ordered bucket entries in gpts
    for (int slot = tid; slot < nclus; slot += BLK) {
        int cl = 0;
        #pragma unroll
        for (int q = 1; q < NCLS; ++q) cl += (int)(slot >= baseC[q]);
        int b0 = baseC[cl], b1 = b0 + cntC[cl];
        int cnt = (int)recM16[slot], id = (int)startv[slot];
        int r = 0;
        for (int s2 = b0; s2 < b1; ++s2) {
            int cnt2 = (int)recM16[s2], id2 = (int)startv[s2];
            r += (int)((cnt2 > cnt) || (cnt2 == cnt && id2 < id));
        }
        float4 g = gstats[id];
        float4 oe;
        oe.x = g.x; oe.y = g.y; oe.z = g.z;
        oe.w = __uint_as_float(((unsigned)id << 1) | 1u);   // id | kept-bit (class implicit)
        gpts[b0 + r] = oe;
    }
    __syncthreads();

    // (d) remap16 identity (startv reused)
    unsigned short* remap16 = startv;
    for (int c2 = tid; c2 < NPTS; c2 += BLK) remap16[c2] = (unsigned short)c2;
    __syncthreads();

    // (e) per-class merge: classes independent; wave w handles classes w, w+4, w+8
    for (int cl = wid; cl < NCLS; cl += NW) {
        int b0 = baseC[cl], b1 = b0 + cntC[cl];
        unsigned Wc = wthr[cl];
        for (int i = b0; i < b1; ++i) {
            float4 ei = gpts[i];
            unsigned wi = __float_as_uint(ei.w);
            if (wi & 1u) {                             // kept -> active absorber
                int orgI = (int)(wi >> 1);
                for (int j = i + 1 + lane; j < b1; j += 64) {
                    float4 ej = gpts[j];
                    unsigned wj = __float_as_uint(ej.w);
                    if (wj & 1u) {
                        float ddx = ej.x - ei.x, ddy = ej.y - ei.y, ddz = ej.z - ei.z;
                        float sdd = (ddx*ddx + ddy*ddy) + ddz*ddz;
                        if (__float_as_uint(sdd) <= Wc) {   // == (sqrtf(sdd) < r2_cl)
                            gpts[j].w = __uint_as_float(wj & ~1u);
                            remap16[wj >> 1] = (unsigned short)orgI;
                        }
                    }
                }
            }
        }
    }
    __syncthreads();

    // (f) final relabel
    for (int p = tid; p < NPTS; p += BLK) out[p] = (int)remap16[dlg[p]];
}

extern "C" void kernel_launch(void* const* d_in, const int* in_sizes, int n_in,
                              void* d_out, int out_size, void* d_ws, size_t ws_size,
                              hipStream_t stream) {
    const float* pts  = (const float*)d_in[0];   // [3072,3] f32
    const int*   lbl  = (const int*)d_in[1];     // [3072] i32
    const float* anch = (const float*)d_in[2];   // [10,3] f32
    frustum_cluster<<<dim3(1), dim3(BLK), 0, stream>>>(pts, lbl, anch,
                                                       (int*)d_out, (int*)d_ws);
}

// Round 11
// 1808.655 us; speedup vs baseline: 1.9244x; 1.9244x over previous
//
#include <hip/hip_runtime.h>
#include <math.h>

#define NPTS 3072
#define BLK  256
#define NW   4
#define NSL  8          // slots per lane: 8*64 = 512 >= max class size (~307+-17, +12 sigma)
#define NKB  48         // fallback batches: 48*64 = 3072
#define NCLS 10

#pragma clang fp contract(off)

__device__ __forceinline__ unsigned umin32(unsigned a, unsigned b) { return a < b ? a : b; }

// 4-step DPP row_shr chain: lanes 15/31/47/63 end with the min of their 16-lane row.
__device__ __forceinline__ unsigned rowmin4_u32(unsigned x) {
    unsigned t;
    t = (unsigned)__builtin_amdgcn_update_dpp(-1, (int)x, 0x111, 0xF, 0xF, false); x = x < t ? x : t; // row_shr:1
    t = (unsigned)__builtin_amdgcn_update_dpp(-1, (int)x, 0x112, 0xF, 0xF, false); x = x < t ? x : t; // row_shr:2
    t = (unsigned)__builtin_amdgcn_update_dpp(-1, (int)x, 0x114, 0xF, 0xF, false); x = x < t ? x : t; // row_shr:4
    t = (unsigned)__builtin_amdgcn_update_dpp(-1, (int)x, 0x118, 0xF, 0xF, false); x = x < t ? x : t; // row_shr:8
    return x;
}

// wave-wide u32 min: 4 DPP steps, then 4 parallel readlanes + scalar min tree (R2/R4-validated).
__device__ __forceinline__ unsigned wavemin_u32(unsigned x) {
    unsigned r = rowmin4_u32(x);
    unsigned a = (unsigned)__builtin_amdgcn_readlane((int)r, 15);
    unsigned b = (unsigned)__builtin_amdgcn_readlane((int)r, 31);
    unsigned c = (unsigned)__builtin_amdgcn_readlane((int)r, 47);
    unsigned d = (unsigned)__builtin_amdgcn_readlane((int)r, 63);
    return umin32(umin32(a, b), umin32(c, d));
}

__device__ __forceinline__ float readlanef(float v, int l) {
    return __int_as_float(__builtin_amdgcn_readlane(__float_as_int(v), l));
}

// In-walk sweep over NS live slots (NS = ceil(cnt_c/64), dispatched per walk).
template<int NS>
__device__ __forceinline__ void sweep_step(const float (&sxr)[NSL], const float (&syr)[NSL],
                                           const float (&szr)[NSL], const unsigned (&mmr)[NSL],
                                           float pcx, float pcy, float pcz,
                                           unsigned &kbest, unsigned &mbest,
                                           float &bx, float &by, float &bz)
{
    float ss[NS];
    #pragma unroll
    for (int i = 0; i < NS; ++i) {
        float dx = pcx - sxr[i], dy = pcy - syr[i], dz = pcz - szr[i];
        ss[i] = (dx*dx + dy*dy) + dz*dz;   // ref order, contract off
    }
    float m;
    if constexpr (NS == 5)
        m = fminf(fminf(fminf(ss[0], ss[1]), fminf(ss[2], ss[3])), ss[4]);
    else if constexpr (NS == 6)
        m = fminf(fminf(fminf(ss[0], ss[1]), fminf(ss[2], ss[3])), fminf(ss[4], ss[5]));
    else
        m = fminf(fminf(fminf(ss[0], ss[1]), fminf(ss[2], ss[3])),
                  fminf(fminf(ss[4], ss[5]), fminf(ss[6], ss[7])));
    kbest = __float_as_uint(m);            // nonneg floats: bits order == value order
    unsigned mb = 0xFFFFFFFFu;
    #pragma unroll
    for (int i = 0; i < NS; ++i) {
        unsigned ci = (ss[i] == m) ? mmr[i] : 0xFFFFFFFFu;
        mb = umin32(mb, ci);
    }
    mbest = mb;
    bx = sxr[0]; by = syr[0]; bz = szr[0];
    #pragma unroll
    for (int i = 1; i < NS; ++i) {         // metas unique (sentinel != any winner)
        bool w = (mmr[i] == mb);
        bx = w ? sxr[i] : bx; by = w ? syr[i] : by; bz = w ? szr[i] : bz;
    }
}

template<int NS>
__device__ __forceinline__ void poison_step(float (&sxr)[NSL], const unsigned (&mmr)[NSL],
                                            unsigned wm)
{
    #pragma unroll
    for (int i = 0; i < NS; ++i)
        if (mmr[i] == wm) sxr[i] = 3e19f;  // poisoned slot: ss -> +inf
}

// R6 phase-A inner iteration: argmin core ONLY (diag-core-equivalent) + pos record.
// All cluster bookkeeping (nc, centres, labels) moved to phase B (walk replay).
#define WALK_INNER(NS)                                                          \
    _Pragma("unroll 4")                                                         \
    for (int k = 0; k < iters; ++k) {                                           \
        unsigned kbest, mbest; float bx, by, bz;                                \
        sweep_step<NS>(sxr, syr, szr, mmr, pcx, pcy, pcz, kbest, mbest, bx, by, bz); \
        unsigned wk = wavemin_u32(kbest);                                       \
        bool cand = (kbest == wk);                                              \
        unsigned long long msk = __ballot(cand);                                \
        if (msk & (msk - 1)) {                   /* exact-bit key tie: rare */  \
            unsigned wm2 = wavemin_u32(cand ? mbest : 0xFFFFFFFFu);             \
            msk = __ballot(cand && (mbest == wm2));                             \
        }                                                                       \
        int wl = __ffsll((unsigned long long)msk) - 1;                          \
        unsigned wm = (unsigned)__builtin_amdgcn_readlane((int)mbest, wl);      \
        float pix = readlanef(bx, wl), piy = readlanef(by, wl), piz = readlanef(bz, wl); \
        pos = (int)(wm & 0xFFFu);                                               \
        poison_step<NS>(sxr, mmr, wm);                                          \
        *((lane == 0) ? &recM16[u] : &sdump[lane]) = (unsigned short)pos;       \
        pcx = pix; pcy = piy; pcz = piz;                                        \
        ++u;                                                                    \
    }

__global__ __launch_bounds__(BLK)
void frustum_cluster(const float* __restrict__ pts,
                     const int* __restrict__ lblg,
                     const float* __restrict__ anch,
                     int* __restrict__ out,
                     int* __restrict__ ws)
{
    const int tid  = threadIdx.x;
    const int lane = tid & 63;
    const int wid  = tid >> 6;

    // ---------------- global workspace ----------------
    int*    dlg    = ws + 16;                          // 3072 ints: per-point label
    float4* gstats = (float4*)(ws + 8192);             // per-cluster stats

    // ---------------- LDS (~62 KB) ----------------
    __shared__ float4 gpts[NPTS];                      // class-grouped points; epilogue: ordered clusters
    __shared__ unsigned short recM16[NPTS];            // visit order -> pos (A writes, B+(a) read; (b)/(c): counts scratch)
    __shared__ unsigned short startv[NPTS];            // cluster starts (B stages+compacts); (b)/(c): ids; (d)-(f): remap16
    __shared__ unsigned short sdump[64];               // dummy target for predicated writes
    __shared__ unsigned short walkS16[65];             // walk w's first visit index (fallback record); NPTS = absent
    __shared__ unsigned short walkCls16[16];           // walk w's class
    __shared__ float amdxy[NCLS], amdz[NCLS];
    __shared__ unsigned vthr[NCLS], wthr[NCLS];        // sqrt-free compare thresholds
    __shared__ int cntL[NCLS], curL[NCLS], baseL[NCLS];
    __shared__ int cntC[NCLS], curC[NCLS], baseC[NCLS];
    __shared__ int cntW[16], baseW[16];                // clusters per walk / prefix
    __shared__ int p0s, nclusS;

    if (tid < NCLS) {
        float l = anch[tid*3+0], w = anch[tid*3+1], h = anch[tid*3+2];
        amdxy[tid] = fmaxf(l, w);
        amdz[tid]  = h;
        float r2 = sqrtf((l*l + w*w) + h*h) * 0.5f;    // norm(anchor)/2, ref op order
        // V: largest float bits v with sqrtf(v) <= r2  =>  (sqrtf(s) > r2) == (bits(s) > V)
        unsigned lo = 0u, hi = 0x7F7FFFFFu;
        while (hi - lo > 1u) {
            unsigned mid = lo + ((hi - lo) >> 1);
            if (sqrtf(__uint_as_float(mid)) <= r2) lo = mid; else hi = mid;
        }
        vthr[tid] = lo;
        // W: largest float bits w with sqrtf(w) < r2  =>  (sqrtf(s) < r2) == (bits(s) <= W)
        lo = 0u; hi = 0x7F7FFFFFu;
        while (hi - lo > 1u) {
            unsigned mid = lo + ((hi - lo) >> 1);
            if (sqrtf(__uint_as_float(mid)) < r2) lo = mid; else hi = mid;
        }
        wthr[tid] = lo;
        cntL[tid] = 0; curL[tid] = 0; cntC[tid] = 0; curC[tid] = 0;
    }
    if (tid < 65) walkS16[tid] = (unsigned short)NPTS;
    if (tid < 16) { walkCls16[tid] = 0; cntW[tid] = 0; }
    __syncthreads();
    for (int j = tid; j < NPTS; j += BLK) atomicAdd(&cntL[lblg[j]], 1);
    __syncthreads();
    if (tid == 0) { int acc = 0; for (int c = 0; c < NCLS; ++c) { baseL[c] = acc; acc += cntL[c]; } }
    __syncthreads();
    // scatter into class-grouped layout; w = prebaked meta (id<<16 | cls<<12 | pos)
    for (int j = tid; j < NPTS; j += BLK) {
        int c = lblg[j];
        int pos = baseL[c] + atomicAdd(&curL[c], 1);
        float4 e;
        e.x = pts[3*j]; e.y = pts[3*j+1]; e.z = pts[3*j+2];
        e.w = __uint_as_float(((unsigned)j << 16) | ((unsigned)c << 12) | (unsigned)pos);
        gpts[pos] = e;
        if (j == 0) p0s = pos;
    }
    __syncthreads();   // scatter + p0s visible

    // ================= PHASE A: single-wave argmin walk (wave 0) =================
    if (wid == 0) {
        int baseLn = 0, cntLn = 0;
        if (lane < NCLS) { baseLn = baseL[lane]; cntLn = cntL[lane]; }
        const int p0 = p0s;
        int pos = p0;
        int cls = lblg[0];
        unsigned walked = 1u << cls;
        float sxr[NSL], syr[NSL], szr[NSL];
        unsigned mmr[NSL];
        float pcx = pts[0], pcy = pts[1], pcz = pts[2];
        int u = 1;                                     // next visit index
        if (lane == 0) recM16[0] = (unsigned short)p0;

        for (int wix = 0; wix < NCLS; ++wix) {         // max 10 walks
            if (lane == 0) {                           // walk boundary record
                walkS16[wix]   = (unsigned short)(u - 1);   // wix=0: 0 (visit 0); else fallback rec idx
                walkCls16[wix] = (unsigned short)cls;
            }
            // ---- walk reload: class cls, excluding current pos ----
            int base_c = __builtin_amdgcn_readlane(baseLn, cls);
            int cnt_c  = __builtin_amdgcn_readlane(cntLn, cls);
            #pragma unroll
            for (int i = 0; i < NSL; ++i) {            // full 8: slots >= nsC stay poisoned
                int off = lane + (i << 6);
                int p = base_c + off;
                bool in = off < cnt_c;
                float4 e = gpts[in ? p : 0];
                bool v = in && (p != pos);             // fresh class: only current point visited
                sxr[i] = v ? e.x : 3e19f;
                syr[i] = v ? e.y : 0.f;
                szr[i] = v ? e.z : 0.f;
                mmr[i] = in ? __float_as_uint(e.w) : 0xFFFFFFFFu;  // sentinel meta for dead slots
            }
            int nsC = (cnt_c + 63) >> 6;
            int iters = cnt_c - 1;

            if (nsC <= 5)      { WALK_INNER(5) }
            else if (nsC == 6) { WALK_INNER(6) }
            else               { WALK_INNER(8) }

            if (u >= NPTS) break;

            // ---- fallback (9x total): nearest point of any un-walked class ----
            {
                unsigned kbest = 0xFFFFFFFFu, mbest = 0xFFFFFFFFu;
                float bx = 0.f, by = 0.f, bz = 0.f;
                for (int k2 = 0; k2 < NKB; ++k2) {
                    int p = lane + (k2 << 6);
                    float4 e = gpts[p];
                    unsigned meta = __float_as_uint(e.w);
                    float dx = pcx - e.x, dy = pcy - e.y, dz = pcz - e.z;
                    float s = (dx*dx + dy*dy) + dz*dz;
                    unsigned key = __float_as_uint(s);
                    bool ok = !((walked >> ((meta >> 12) & 15u)) & 1u);
                    if (ok && (key < kbest || (key == kbest && meta < mbest))) {
                        kbest = key; mbest = meta; bx = e.x; by = e.y; bz = e.z;
                    }
                }
                unsigned wk = wavemin_u32(kbest);
                bool cand = (kbest == wk);
                unsigned wm = wavemin_u32(cand ? mbest : 0xFFFFFFFFu);
                unsigned long long msk = __ballot(cand && (mbest == wm));
                int wl = __ffsll((unsigned long long)msk) - 1;
                float pix = readlanef(bx, wl), piy = readlanef(by, wl), piz = readlanef(bz, wl);
                pos = (int)(wm & 0xFFFu);
                cls = (int)((wm >> 12) & 15u);
                walked |= 1u << cls;
                *((lane == 0) ? &recM16[u] : &sdump[lane]) = (unsigned short)pos;
                pcx = pix; pcy = piy; pcz = piz;
                ++u;
            }
        }
    }
    __syncthreads();   // join A

    // ================= PHASE B: lane-parallel walk replay (wave 0) =================
    // Lane w replays walk w (<=10 active lanes), recomputing nc bitwise-identically:
    // seS bits == A's winner key (same gpts-sourced operands, same op order, contract off);
    // seC from carried sums with top-of-iter div (x/1.0 exact at cluster start).
    // Cluster-start visit indices staged into startv[s_w + j] (disjoint per walk).
    if (wid == 0) {
        int w = lane;
        int sW = (int)walkS16[w];                      // NPTS if absent (w >= #walks)
        int eW = (int)walkS16[w + 1];
        bool exists = sW < NPTS;
        int cls = (int)walkCls16[exists ? w : 0];
        float axy = amdxy[cls], az = amdz[cls];
        unsigned Vc = vthr[cls];
        int pos0 = (int)recM16[exists ? sW : 0];
        float4 pe = gpts[pos0];
        float prevx = pe.x, prevy = pe.y, prevz = pe.z;
        float sx = prevx, sy = prevy, sz = prevz, scnt = 1.0f;
        int cnt = 1;
        if (exists) startv[sW] = (unsigned short)sW;   // walk's first visit starts a cluster
        int u = sW + 1;
        int posn = (int)recM16[(exists && u < eW) ? u : 0];   // prefetched meta
        for (;;) {
            unsigned long long alive = __ballot(u < eW);
            if (!alive) break;
            bool act = (u < eW);
            float4 ec = gpts[act ? posn : 0];
            int posn2 = (int)recM16[(u + 1 < eW) ? (u + 1) : 0];
            float pix = ec.x, piy = ec.y, piz = ec.z;
            float dx = prevx - pix, dy = prevy - piy, dz = prevz - piz;
            float seS = (dx*dx + dy*dy) + dz*dz;       // == A's winner key bits
            bool a1 = (fabsf(dx) > axy) | (fabsf(dy) > axy) | (fabsf(dz) > az);
            float icx = sx / scnt, icy = sy / scnt, icz = sz / scnt;
            float ex = icx - pix, ey = icy - piy, ez = icz - piz;
            float seC = (ex*ex + ey*ey) + ez*ez;
            bool nc = a1 | (__float_as_uint(seS) > Vc) | (__float_as_uint(seC) > Vc);
            if (act & nc) startv[sW + cnt] = (unsigned short)u;
            cnt += (act & nc) ? 1 : 0;
            scnt = nc ? 1.0f : (scnt + 1.0f);          // scnt >= 1 always (no div-by-0)
            sx = nc ? pix : (sx + pix);
            sy = nc ? piy : (sy + piy);
            sz = nc ? piz : (sz + piz);
            prevx = pix; prevy = piy; prevz = piz;
            posn = posn2;
            ++u;
        }
        if (exists) cntW[w] = cnt;
    }
    __syncthreads();   // join B

    if (tid == 0) {    // prefix over per-walk cluster counts
        int acc = 0;
        for (int c = 0; c < NCLS; ++c) { baseW[c] = acc; acc += cntW[c]; }
        nclusS = acc - 1;                              // lab semantics: starts - 1
    }
    __syncthreads();

    // compaction: left-shift staged starts to global positions (walks in order; baseW[w] <= s_w
    // provably, so batched read-then-write never clobbers unread data)
    if (wid == 0) {
        for (int w2 = 0; w2 < NCLS; ++w2) {
            int sW = (int)walkS16[w2];
            if (sW >= NPTS) break;                     // walks contiguous from 0
            int bW = baseW[w2], cW = cntW[w2];
            if (bW == sW) continue;
            for (int j = lane; j < cW; j += 64) {
                unsigned short v = startv[sW + j];
                startv[bW + j] = v;
            }
        }
    }
    __syncthreads();
    const int nclus = nclusS;

    // ---------------- epilogue (R11/R12-proven; vor16 -> recM16 substitution only) ----------------
    // (a) runs in visit order -> per-cluster stats (bitwise == incremental sums) + dl to global
    for (int c2 = tid; c2 <= nclus; c2 += BLK) {
        int s0 = startv[c2];
        int s1e = (c2 < nclus) ? (int)startv[c2+1] : NPTS;
        float ax = 0.f, ay = 0.f, az = 0.f;
        int clsF = 0;
        for (int s = s0; s < s1e; ++s) {
            float4 e = gpts[recM16[s]];
            unsigned pk = __float_as_uint(e.w);
            if (s == s0) clsF = (int)((pk >> 12) & 15u);
            ax = ax + e.x; ay = ay + e.y; az = az + e.z;
            dlg[pk >> 16] = c2;
        }
        if (c2 < nclus) {
            float fc = (float)(s1e - s0);
            float4 g;
            g.x = ax / fc; g.y = ay / fc; g.z = az / fc;
            g.w = __uint_as_float(((unsigned)(s1e - s0) << 4) | (unsigned)clsF);
            gstats[c2] = g;
        }
    }
    __syncthreads();

    // (a2) bucket counts per class over clusters
    for (int c2 = tid; c2 < nclus; c2 += BLK)
        atomicAdd(&cntC[__float_as_uint(gstats[c2].w) & 15u], 1);
    __syncthreads();
    if (tid == 0) { int acc = 0; for (int c = 0; c < NCLS; ++c) { baseC[c] = acc; acc += cntC[c]; } }
    __syncthreads();

    // (b) scatter clusters into class buckets (recM16 = count, startv = cluster id)
    for (int c2 = tid; c2 < nclus; c2 += BLK) {
        unsigned gw = __float_as_uint(gstats[c2].w);
        int cl = (int)(gw & 15u);
        int slot = baseC[cl] + atomicAdd(&curC[cl], 1);
        recM16[slot] = (unsigned short)(gw >> 4);
        startv[slot] = (unsigned short)c2;
    }
    __syncthreads();

    // (c) class-local stable rank (counts desc, id asc) -> ordered bucket entries in gpts
    for (int slot = tid; slot < nclus; slot += BLK) {
        int cl = 0;
        #pragma unroll
        for (int q = 1; q < NCLS; ++q) cl += (int)(slot >= baseC[q]);
        int b0 = baseC[cl], b1 = b0 + cntC[cl];
        int cnt = (int)recM16[slot], id = (int)startv[slot];
        int r = 0;
        for (int s2 = b0; s2 < b1; ++s2) {
            int cnt2 = (int)recM16[s2], id2 = (int)startv[s2];
            r += (int)((cnt2 > cnt) || (cnt2 == cnt && id2 < id));
        }
        float4 g = gstats[id];
        float4 oe;
        oe.x = g.x; oe.y = g.y; oe.z = g.z;
        oe.w = __uint_as_float(((unsigned)id << 1) | 1u);   // id | kept-bit (class implicit)
        gpts[b0 + r] = oe;
    }
    __syncthreads();

    // (d) remap16 identity (startv reused)
    unsigned short* remap16 = startv;
    for (int c2 = tid; c2 < NPTS; c2 += BLK) remap16[c2] = (unsigned short)c2;
    __syncthreads();

    // (e) per-class merge: classes independent; wave w handles classes w, w+4, w+8 — zero barriers
    for (int cl = wid; cl < NCLS; cl += NW) {
        int b0 = baseC[cl], b1 = b0 + cntC[cl];
        unsigned Wc = wthr[cl];
        for (int i = b0; i < b1; ++i) {
            float4 ei = gpts[i];
            unsigned wi = __float_as_uint(ei.w);
            if (wi & 1u) {                             // kept -> active absorber
                int orgI = (int)(wi >> 1);
                for (int j = i + 1 + lane; j < b1; j += 64) {
                    float4 ej = gpts[j];
                    unsigned wj = __float_as_uint(ej.w);
                    if (wj & 1u) {
                        float ddx = ej.x - ei.x, ddy = ej.y - ei.y, ddz = ej.z - ei.z;
                        float sdd = (ddx*ddx + ddy*ddy) + ddz*ddz;
                        if (__float_as_uint(sdd) <= Wc) {   // == (sqrtf(sdd) < r2_cl)
                            gpts[j].w = __uint_as_float(wj & ~1u);
                            remap16[wj >> 1] = (unsigned short)orgI;
                        }
                    }
                }
            }
        }
    }
    __syncthreads();

    // (f) final relabel
    for (int p = tid; p < NPTS; p += BLK) out[p] = (int)remap16[dlg[p]];
}

extern "C" void kernel_launch(void* const* d_in, const int* in_sizes, int n_in,
                              void* d_out, int out_size, void* d_ws, size_t ws_size,
                              hipStream_t stream) {
    const float* pts  = (const float*)d_in[0];   // [3072,3] f32
    const int*   lbl  = (const int*)d_in[1];     // [3072] i32
    const float* anch = (const float*)d_in[2];   // [10,3] f32
    frustum_cluster<<<dim3(1), dim3(BLK), 0, stream>>>(pts, lbl, anch,
                                                       (int*)d_out, (int*)d_ws);
}